// Round 12
// baseline (212.618 us; speedup 1.0000x reference)
//
#include <hip/hip_runtime.h>
#include <hip/hip_bf16.h>
#include <math.h>

#define C_CLASSES 100000
#define EMBED     384
#define BATCH     512
#define S_SCALE   64.0f
#define COS_M_    0.8775825618903728f
#define SIN_M_    0.479425538604203f
#define TH_       (-0.8775825618903728f)
#define MM_       0.2397127693021015f
#define EPS_      1e-7f
#define LOG2E_    1.4426950408889634f
#define LN2_      0.6931471805599453f
#define BIGZ_     92.33261191693459f      /* 64 * log2(e) */
#define SK1_      92.33248165f            /* 64 * log2(e), fp32 of S*LOG2E */

#define CT    64
#define NCH   1563                         // ceil(100000/64)
#define NB    256                          // persistent blocks

typedef __attribute__((ext_vector_type(8))) short bf16x8;
typedef __attribute__((ext_vector_type(4))) float f32x4;

__device__ inline ushort f2bf(float f) {
    unsigned u = __float_as_uint(f);
    unsigned r = (u + 0x7fffu + ((u >> 16) & 1u)) >> 16;   // RNE
    return (ushort)r;
}

// ---------------------------------------------------------------------------
// Kernel 0: convert E to bf16, packed in MFMA A-fragment order.
// ---------------------------------------------------------------------------
__global__ __launch_bounds__(256)
void cvt_pack_e(const float* __restrict__ emb, ushort* __restrict__ eP)
{
    int t = blockIdx.x * 256 + threadIdx.x;      // 0 .. 24575
    int lane = t & 63;
    int grp  = t >> 6;                           // tile*12 + ks
    int tile = grp / 12, ks = grp % 12;
    int lr = lane & 15, lg = lane >> 4;
    int row = tile * 16 + lr;
    int col = ks * 32 + lg * 8;
    const float4* src = (const float4*)(emb + (size_t)row * EMBED + col);
    float4 v0 = src[0], v1 = src[1];
    ushort4 o0, o1;
    o0.x = f2bf(v0.x); o0.y = f2bf(v0.y); o0.z = f2bf(v0.z); o0.w = f2bf(v0.w);
    o1.x = f2bf(v1.x); o1.y = f2bf(v1.y); o1.z = f2bf(v1.z); o1.w = f2bf(v1.w);
    ((ushort4*)eP)[t * 2]     = o0;
    ((ushort4*)eP)[t * 2 + 1] = o1;
}

// ---------------------------------------------------------------------------
// Per-chunk MFMA + epilogue. acc 4Mt x 2Nt; wave (mg,nh): rows mg*64..+63,
// classes c0 + nh*32 .. +31. TAIL guards the padded last chunk.
// ---------------------------------------------------------------------------
template<bool TAIL>
__device__ __forceinline__ void chunk_compute(
    const ushort* __restrict__ aTh, const ushort* __restrict__ blc,
    const int* __restrict__ labL, const int* __restrict__ boff,
    int c0, int ch, int mg, int nh, int lr, int lg,
    float* __restrict__ psum, float* __restrict__ zlabel)
{
    f32x4 acc[4][2];
    #pragma unroll
    for (int mt = 0; mt < 4; ++mt) {
        acc[mt][0] = (f32x4){0.f, 0.f, 0.f, 0.f};
        acc[mt][1] = (f32x4){0.f, 0.f, 0.f, 0.f};
    }

    const char* bb = (const char*)blc;
    #pragma unroll
    for (int ks = 0; ks < 12; ++ks) {
        bf16x8 a0 = *(const bf16x8*)(aTh + (0 * 12 + ks) * 512);
        bf16x8 a1 = *(const bf16x8*)(aTh + (1 * 12 + ks) * 512);
        bf16x8 a2 = *(const bf16x8*)(aTh + (2 * 12 + ks) * 512);
        bf16x8 a3 = *(const bf16x8*)(aTh + (3 * 12 + ks) * 512);
        bf16x8 b0 = *(const bf16x8*)(bb + ((nh * 2 + 0) * 12 + ks) * 1024 + boff[ks & 3]);
        bf16x8 b1 = *(const bf16x8*)(bb + ((nh * 2 + 1) * 12 + ks) * 1024 + boff[ks & 3]);
        acc[0][0] = __builtin_amdgcn_mfma_f32_16x16x32_bf16(a0, b0, acc[0][0], 0, 0, 0);
        acc[1][0] = __builtin_amdgcn_mfma_f32_16x16x32_bf16(a1, b0, acc[1][0], 0, 0, 0);
        acc[2][0] = __builtin_amdgcn_mfma_f32_16x16x32_bf16(a2, b0, acc[2][0], 0, 0, 0);
        acc[3][0] = __builtin_amdgcn_mfma_f32_16x16x32_bf16(a3, b0, acc[3][0], 0, 0, 0);
        acc[0][1] = __builtin_amdgcn_mfma_f32_16x16x32_bf16(a0, b1, acc[0][1], 0, 0, 0);
        acc[1][1] = __builtin_amdgcn_mfma_f32_16x16x32_bf16(a1, b1, acc[1][1], 0, 0, 0);
        acc[2][1] = __builtin_amdgcn_mfma_f32_16x16x32_bf16(a2, b1, acc[2][1], 0, 0, 0);
        acc[3][1] = __builtin_amdgcn_mfma_f32_16x16x32_bf16(a3, b1, acc[3][1], 0, 0, 0);
    }

    const int cbase = c0 + nh * 32;
    #pragma unroll
    for (int mt = 0; mt < 4; ++mt) {
        #pragma unroll
        for (int rg = 0; rg < 4; ++rg) {
            const int r   = mg * 64 + mt * 16 + lg * 4 + rg;
            const int lab = labL[r];
            float acc4 = 0.f;
            #pragma unroll
            for (int nt = 0; nt < 2; ++nt) {
                float cv = acc[mt][nt][rg];
                cv = fminf(fmaxf(cv, -1.f + EPS_), 1.f - EPS_);
                float z = fmaf(cv, SK1_, -BIGZ_);
                if (TAIL) {
                    int gc = cbase + nt * 16 + lr;
                    if (gc >= C_CLASSES) z = -1e30f;
                }
                acc4 += exp2f(z);
            }
            // rare label fix-up: replace plain term by margin term
            int off = lab - cbase;
            if (((unsigned)off < 32u) && ((lab & 15) == lr)) {
                float cv = (off >> 4) ? acc[mt][1][rg] : acc[mt][0][rg];
                cv = fminf(fmaxf(cv, -1.f + EPS_), 1.f - EPS_);
                float plain = exp2f(fmaf(cv, SK1_, -BIGZ_));
                float zm;
                if (cv > TH_) {
                    float sv = sqrtf(fmaxf(1.f - cv * cv, 0.f));
                    zm = S_SCALE * (cv * COS_M_ - sv * SIN_M_);
                } else {
                    zm = S_SCALE * (cv - MM_);
                }
                acc4 += exp2f(fmaf(zm, LOG2E_, -BIGZ_)) - plain;
                zlabel[r] = zm;
            }
            acc4 += __shfl_xor(acc4, 1, 64);
            acc4 += __shfl_xor(acc4, 2, 64);
            acc4 += __shfl_xor(acc4, 4, 64);
            acc4 += __shfl_xor(acc4, 8, 64);
            if (lr == 0)
                psum[((size_t)ch * 2 + nh) * BATCH + r] = acc4;
        }
    }
}

// ---------------------------------------------------------------------------
// Kernel 1: persistent chunk pipeline.
// grid = 256 x 1024 (16 waves, 1 block/CU). Per iter: MFMA+epilogue(Bl[cur])
// overlaps the in-flight register prefetch of the NEXT chunk's raw W; then
// pack -> Bl[nxt] (bank-swizzled), issue k+2 loads, raw barrier (lgkm only,
// vmem loads stay in flight across it).
// ---------------------------------------------------------------------------
__global__ __launch_bounds__(1024, 4)
void arc_pipe(const ushort* __restrict__ eP, const int* __restrict__ labels,
              const float* __restrict__ weight,
              float* __restrict__ psum, float* __restrict__ zlabel)
{
    __shared__ ushort Bl[2][4 * 12 * 512];     // 2 x 49152 B
    __shared__ int    labL[BATCH];

    const int tid = threadIdx.x;
    const int blk = blockIdx.x;
    const int nch = 6 + ((blk < (NCH - 6 * NB)) ? 1 : 0);   // 27 blocks do 7

    if (tid < BATCH) labL[tid] = labels[tid];

    const int wid = tid >> 6, l = tid & 63;
    const int lr  = l & 15,  lg = l >> 4;
    const int mg  = wid & 7;           // rows mg*64..+63
    const int nh  = wid >> 3;          // classes nh*32..+31 within chunk

    const int c = tid >> 4;            // stage: class 0..63 in chunk
    const int p = tid & 15;            // 16 lanes per class

    // pack byte-offsets into a Bl buffer (6 x b64 writes, bank-swizzled)
    int pkoff[6];
    {
        const int t2 = c >> 4, cl = c & 15;
        #pragma unroll
        for (int i = 0; i < 6; ++i) {
            int q   = p + 16 * i;
            int ksw = q >> 3;
            int lgp = (q >> 1) & 3;
            int byt = ((t2 * 12 + ksw) * 64 + cl + 16 * lgp) * 16 + (q & 1) * 8;
            byt ^= ((ksw + lgp) & 3) << 5;
            pkoff[i] = byt;
        }
    }
    // b-read lane offsets per (ks&3), matching the pack swizzle
    int boff[4];
    #pragma unroll
    for (int j = 0; j < 4; ++j)
        boff[j] = (l * 16) ^ (((j + lg) & 3) << 5);

    const ushort* aTh = eP + (size_t)mg * 24576 + (size_t)l * 8;

    float4 wv[6];

#define LOAD_W(CH) do {                                                       \
        int row_ = (CH) * CT + c;                                             \
        if (row_ >= C_CLASSES) row_ = C_CLASSES - 1;                          \
        const float4* s_ = (const float4*)(weight + (size_t)row_ * EMBED) + p;\
        wv[0] = s_[0];  wv[1] = s_[16]; wv[2] = s_[32];                       \
        wv[3] = s_[48]; wv[4] = s_[64]; wv[5] = s_[80];                       \
    } while (0)

#define PACK_W(BUF) do {                                                      \
        float ss_ = 0.f;                                                      \
        _Pragma("unroll")                                                     \
        for (int i_ = 0; i_ < 6; ++i_)                                        \
            ss_ += wv[i_].x * wv[i_].x + wv[i_].y * wv[i_].y                  \
                 + wv[i_].z * wv[i_].z + wv[i_].w * wv[i_].w;                 \
        ss_ += __shfl_xor(ss_, 1, 64); ss_ += __shfl_xor(ss_, 2, 64);         \
        ss_ += __shfl_xor(ss_, 4, 64); ss_ += __shfl_xor(ss_, 8, 64);         \
        const float inv_ = (ss_ > 0.f) ? rsqrtf(ss_) : 0.f;                   \
        _Pragma("unroll")                                                     \
        for (int i_ = 0; i_ < 6; ++i_) {                                      \
            ushort4 o_;                                                       \
            o_.x = f2bf(wv[i_].x * inv_); o_.y = f2bf(wv[i_].y * inv_);       \
            o_.z = f2bf(wv[i_].z * inv_); o_.w = f2bf(wv[i_].w * inv_);       \
            *(ushort4*)((char*)&Bl[BUF][0] + pkoff[i_]) = o_;                 \
        }                                                                     \
    } while (0)

    // ---- prologue ----
    int ch = blk;
    LOAD_W(ch);
    PACK_W(0);
    if (nch > 1) LOAD_W(ch + NB);              // in flight across barrier
    asm volatile("s_waitcnt lgkmcnt(0)" ::: "memory");
    __builtin_amdgcn_sched_barrier(0);
    __builtin_amdgcn_s_barrier();

    for (int k = 0; k < nch; ++k) {
        const int c0 = ch * CT;
        const ushort* blc = &Bl[k & 1][0];
        if (ch == NCH - 1)
            chunk_compute<true >(aTh, blc, labL, boff, c0, ch, mg, nh, lr, lg,
                                 psum, zlabel);
        else
            chunk_compute<false>(aTh, blc, labL, boff, c0, ch, mg, nh, lr, lg,
                                 psum, zlabel);
        if (k + 1 < nch) {
            PACK_W((k + 1) & 1);               // waits its own loads only
            if (k + 2 < nch) LOAD_W(ch + 2 * NB);   // stays in flight
            asm volatile("s_waitcnt lgkmcnt(0)" ::: "memory");
            __builtin_amdgcn_sched_barrier(0);
            __builtin_amdgcn_s_barrier();
        }
        ch += NB;
    }
#undef LOAD_W
#undef PACK_W
}

// ---------------------------------------------------------------------------
// Kernel 2: sum 2*NCH partials per row -> row loss
// ---------------------------------------------------------------------------
__global__ __launch_bounds__(256)
void arc_reduce(const float* __restrict__ psum, const float* __restrict__ zlabel,
                float* __restrict__ rowloss)
{
    const int r = blockIdx.x;
    const int tid = threadIdx.x;
    float s = 0.f;
    for (int k = tid; k < 2 * NCH; k += 256)
        s += psum[(size_t)k * BATCH + r];
    #pragma unroll
    for (int d = 1; d < 64; d <<= 1) s += __shfl_xor(s, d, 64);
    __shared__ float ssh[4];
    if ((tid & 63) == 0) ssh[tid >> 6] = s;
    __syncthreads();
    if (tid == 0) {
        float t = ssh[0] + ssh[1] + ssh[2] + ssh[3];
        rowloss[r] = LN2_ * (BIGZ_ + log2f(t)) - zlabel[r];
    }
}

// ---------------------------------------------------------------------------
// Kernel 3: mean over rows
// ---------------------------------------------------------------------------
__global__ __launch_bounds__(512)
void arc_mean(const float* __restrict__ rowloss, float* __restrict__ out)
{
    const int tid = threadIdx.x;
    float v = rowloss[tid];
    #pragma unroll
    for (int d = 1; d < 64; d <<= 1) v += __shfl_xor(v, d, 64);
    __shared__ float sv[8];
    if ((tid & 63) == 0) sv[tid >> 6] = v;
    __syncthreads();
    if (tid == 0) {
        float t = 0.f;
        #pragma unroll
        for (int w = 0; w < 8; ++w) t += sv[w];
        out[0] = t / (float)BATCH;
    }
}

extern "C" void kernel_launch(void* const* d_in, const int* in_sizes, int n_in,
                              void* d_out, int out_size, void* d_ws, size_t ws_size,
                              hipStream_t stream)
{
    (void)in_sizes; (void)n_in; (void)out_size; (void)ws_size;
    const float* emb    = (const float*)d_in[0];
    const int*   labels = (const int*)d_in[1];
    const float* weight = (const float*)d_in[2];
    float* out = (float*)d_out;

    float*  psum    = (float*)d_ws;                      // [2*NCH][BATCH] 6.4MB
    float*  zlabel  = psum + (size_t)2 * NCH * BATCH;    // [BATCH]
    float*  rowloss = zlabel + BATCH;                    // [BATCH]
    ushort* eP      = (ushort*)(rowloss + BATCH);        // packed bf16 E frags

    cvt_pack_e<<<(BATCH * EMBED / 8) / 256, 256, 0, stream>>>(emb, eP);
    arc_pipe<<<NB, 1024, 0, stream>>>(eP, labels, weight, psum, zlabel);
    arc_reduce<<<BATCH, 256, 0, stream>>>(psum, zlabel, rowloss);
    arc_mean<<<1, 512, 0, stream>>>(rowloss, out);
}

// Round 13
// 99.906 us; speedup vs baseline: 2.1282x; 2.1282x over previous
//
#include <hip/hip_runtime.h>
#include <hip/hip_bf16.h>
#include <math.h>

#define C_CLASSES 100000
#define EMBED     384
#define BATCH     512
#define S_SCALE   64.0f
#define COS_M_    0.8775825618903728f
#define SIN_M_    0.479425538604203f
#define TH_       (-0.8775825618903728f)
#define MM_       0.2397127693021015f
#define EPS_      1e-7f
#define LOG2E_    1.4426950408889634f
#define LN2_      0.6931471805599453f
#define BIGZ_     92.33261191693459f      /* 64 * log2(e) */
#define SK1_      92.33248f               /* fp32(S * log2(e)) */

#define CT    64
#define NCH   1563                         // ceil(100000/64); last chunk padded

typedef __attribute__((ext_vector_type(8))) short bf16x8;
typedef __attribute__((ext_vector_type(4))) float f32x4;

__device__ inline ushort f2bf(float f) {
    unsigned u = __float_as_uint(f);
    unsigned r = (u + 0x7fffu + ((u >> 16) & 1u)) >> 16;   // RNE
    return (ushort)r;
}

// ---------------------------------------------------------------------------
// Kernel 0: convert E to bf16, packed in MFMA A-fragment order:
//   eP[((tile*12 + ks)*64 + lane)*8 + j] = bf16(E[tile*16 + (lane&15)]
//                                               [ks*32 + (lane>>4)*8 + j])
// ---------------------------------------------------------------------------
__global__ __launch_bounds__(256)
void cvt_pack_e(const float* __restrict__ emb, ushort* __restrict__ eP)
{
    int t = blockIdx.x * 256 + threadIdx.x;      // 0 .. 24575
    int lane = t & 63;
    int grp  = t >> 6;                           // tile*12 + ks
    int tile = grp / 12, ks = grp % 12;
    int lr = lane & 15, lg = lane >> 4;
    int row = tile * 16 + lr;
    int col = ks * 32 + lg * 8;
    const float4* src = (const float4*)(emb + (size_t)row * EMBED + col);
    float4 v0 = src[0], v1 = src[1];
    ushort4 o0, o1;
    o0.x = f2bf(v0.x); o0.y = f2bf(v0.y); o0.z = f2bf(v0.z); o0.w = f2bf(v0.w);
    o1.x = f2bf(v1.x); o1.y = f2bf(v1.y); o1.z = f2bf(v1.z); o1.w = f2bf(v1.w);
    ((ushort4*)eP)[t * 2]     = o0;
    ((ushort4*)eP)[t * 2 + 1] = o1;
}

// ---------------------------------------------------------------------------
// Kernel 1: fused, spill-free. Per block (64-class chunk, 512 thr, 8 waves):
//  phase 1: W global->reg in TWO half-passes (16 lanes/row, wv[6]=24 VGPR),
//           sumsq butterfly, scale -> bf16 -> fragment-packed LDS (48 KB);
//           labels -> LDS; one __syncthreads.
//  phase 2: MFMA 8 waves x 4Mt x 4Nt x 12ks; A from L2-resident eP.
//  phase 3: clamp + fixed-max LSE; margin handled as a rare per-row fixup;
//           tail masking only in the last (padded) block.
// ---------------------------------------------------------------------------
__global__ __launch_bounds__(512, 4)
void arc_fused64(const ushort* __restrict__ eP, const int* __restrict__ labels,
                 const float* __restrict__ weight,
                 float* __restrict__ psum, float* __restrict__ zlabel)
{
    __shared__ ushort Bl[(CT / 16) * 12 * 512];    // 24576 ushorts = 49152 B
    __shared__ int    labL[BATCH];

    const int tid = threadIdx.x;

    // bijective XCD-aware swizzle (m204 form): same-XCD blocks get
    // consecutive chunks -> W row locality + shared eP in XCD L2.
    const int orig = blockIdx.x;
    const int xcd  = orig & 7;
    const int qq   = NCH >> 3, rr = NCH & 7;       // 195, 3
    const int blk  = (xcd < rr ? xcd * (qq + 1)
                               : rr * (qq + 1) + (xcd - rr) * qq) + (orig >> 3);
    const int c0   = blk * CT;

    labL[tid] = labels[tid];

    // ---- phase 1: two half-passes of 32 rows each (16 lanes/row) ----
    {
        const int p = tid & 15;              // 16 lanes per class
        #pragma unroll
        for (int h = 0; h < 2; ++h) {
            const int c = h * 32 + (tid >> 4);       // class 0..63
            int row = c0 + c;
            if (row >= C_CLASSES) row = C_CLASSES - 1;   // pad rows: clamp
            const float4* src = (const float4*)(weight + (size_t)row * EMBED) + p;

            float4 wv[6];
            float ss = 0.f;
            #pragma unroll
            for (int i = 0; i < 6; ++i) {
                wv[i] = src[16 * i];
                ss += wv[i].x * wv[i].x + wv[i].y * wv[i].y
                    + wv[i].z * wv[i].z + wv[i].w * wv[i].w;
            }
            ss += __shfl_xor(ss, 1, 64);
            ss += __shfl_xor(ss, 2, 64);
            ss += __shfl_xor(ss, 4, 64);
            ss += __shfl_xor(ss, 8, 64);
            const float inv = (ss > 0.f) ? rsqrtf(ss) : 0.f;

            const int t2 = c >> 4, cl = c & 15;
            #pragma unroll
            for (int i = 0; i < 6; ++i) {
                int q   = p + 16 * i;        // quad index 0..95 (k = 4q..4q+3)
                int ks  = q >> 3;
                int lgp = (q >> 1) & 3;
                int jo  = (q & 1) * 4;
                ushort4 o;
                o.x = f2bf(wv[i].x * inv); o.y = f2bf(wv[i].y * inv);
                o.z = f2bf(wv[i].z * inv); o.w = f2bf(wv[i].w * inv);
                *(ushort4*)&Bl[(size_t)(((t2 * 12 + ks) * 64) + cl + 16 * lgp) * 8 + jo] = o;
            }
        }
    }
    __syncthreads();     // packed B + labL ready

    // ---- phase 2: MFMA, 8 waves x (4 Mtiles x 4 Ntiles), K=384 ----
    const int wid = tid >> 6, l = tid & 63;
    const int lr  = l & 15,  lg = l >> 4;

    const ushort* abase = eP + ((size_t)(wid * 4) * 12 * 64 + l) * 8;

    f32x4 acc[4][4];
    #pragma unroll
    for (int mt = 0; mt < 4; ++mt)
        #pragma unroll
        for (int nt = 0; nt < 4; ++nt)
            acc[mt][nt] = (f32x4){0.f, 0.f, 0.f, 0.f};

    #pragma unroll
    for (int ks = 0; ks < 12; ++ks) {
        bf16x8 a[4], b[4];
        #pragma unroll
        for (int mt = 0; mt < 4; ++mt)
            a[mt] = *(const bf16x8*)(abase + (mt * 12 + ks) * 512);
        #pragma unroll
        for (int nt = 0; nt < 4; ++nt)
            b[nt] = *(const bf16x8*)&Bl[(size_t)((nt * 12 + ks) * 64 + l) * 8];
        #pragma unroll
        for (int mt = 0; mt < 4; ++mt)
            #pragma unroll
            for (int nt = 0; nt < 4; ++nt)
                acc[mt][nt] = __builtin_amdgcn_mfma_f32_16x16x32_bf16(
                    a[mt], b[nt], acc[mt][nt], 0, 0, 0);
    }

    // ---- phase 3: fixed-max LSE + rare margin fixup ----
    const bool tail = (blk == NCH - 1);
    #pragma unroll
    for (int mt = 0; mt < 4; ++mt) {
        #pragma unroll
        for (int rg = 0; rg < 4; ++rg) {
            const int r   = wid * 64 + mt * 16 + lg * 4 + rg;
            const int lab = labL[r];
            float acc4 = 0.f;
            if (!tail) {
                #pragma unroll
                for (int nt = 0; nt < 4; ++nt) {
                    float cv = acc[mt][nt][rg];
                    cv = fminf(fmaxf(cv, -1.f + EPS_), 1.f - EPS_);
                    acc4 += exp2f(fmaf(cv, SK1_, -BIGZ_));
                }
            } else {
                #pragma unroll
                for (int nt = 0; nt < 4; ++nt) {
                    float cv = acc[mt][nt][rg];
                    cv = fminf(fmaxf(cv, -1.f + EPS_), 1.f - EPS_);
                    float z = fmaf(cv, SK1_, -BIGZ_);
                    int gc = c0 + nt * 16 + lr;
                    if (gc >= C_CLASSES) z = -1e30f;
                    acc4 += exp2f(z);
                }
            }
            // rare fixup: this lane holds the label column of row r
            int off = lab - c0;
            if (((unsigned)off < 64u) && ((off & 15) == lr)) {
                int ntl = off >> 4;
                float cv = (ntl == 0) ? acc[mt][0][rg]
                         : (ntl == 1) ? acc[mt][1][rg]
                         : (ntl == 2) ? acc[mt][2][rg]
                                      : acc[mt][3][rg];
                cv = fminf(fmaxf(cv, -1.f + EPS_), 1.f - EPS_);
                float plain = exp2f(fmaf(cv, SK1_, -BIGZ_));
                float zm;
                if (cv > TH_) {
                    float sv = sqrtf(fmaxf(1.f - cv * cv, 0.f));
                    zm = S_SCALE * (cv * COS_M_ - sv * SIN_M_);
                } else {
                    zm = S_SCALE * (cv - MM_);
                }
                acc4 += exp2f(fmaf(zm, LOG2E_, -BIGZ_)) - plain;
                zlabel[r] = zm;
            }
            acc4 += __shfl_xor(acc4, 1, 64);
            acc4 += __shfl_xor(acc4, 2, 64);
            acc4 += __shfl_xor(acc4, 4, 64);
            acc4 += __shfl_xor(acc4, 8, 64);
            if (lr == 0) psum[(size_t)blk * BATCH + r] = acc4;
        }
    }
}

// ---------------------------------------------------------------------------
// Kernel 2: sum 1563 chunk-partials per row -> row loss
// ---------------------------------------------------------------------------
__global__ __launch_bounds__(256)
void arc_reduce(const float* __restrict__ psum, const float* __restrict__ zlabel,
                float* __restrict__ rowloss)
{
    const int r = blockIdx.x;
    const int tid = threadIdx.x;
    float s = 0.f;
    for (int k = tid; k < NCH; k += 256)
        s += psum[(size_t)k * BATCH + r];
    #pragma unroll
    for (int d = 1; d < 64; d <<= 1) s += __shfl_xor(s, d, 64);
    __shared__ float ssh[4];
    if ((tid & 63) == 0) ssh[tid >> 6] = s;
    __syncthreads();
    if (tid == 0) {
        float t = ssh[0] + ssh[1] + ssh[2] + ssh[3];
        rowloss[r] = LN2_ * (BIGZ_ + log2f(t)) - zlabel[r];
    }
}

// ---------------------------------------------------------------------------
// Kernel 3: mean over rows
// ---------------------------------------------------------------------------
__global__ __launch_bounds__(512)
void arc_mean(const float* __restrict__ rowloss, float* __restrict__ out)
{
    const int tid = threadIdx.x;
    float v = rowloss[tid];
    #pragma unroll
    for (int d = 1; d < 64; d <<= 1) v += __shfl_xor(v, d, 64);
    __shared__ float sv[8];
    if ((tid & 63) == 0) sv[tid >> 6] = v;
    __syncthreads();
    if (tid == 0) {
        float t = 0.f;
        #pragma unroll
        for (int w = 0; w < 8; ++w) t += sv[w];
        out[0] = t / (float)BATCH;
    }
}

extern "C" void kernel_launch(void* const* d_in, const int* in_sizes, int n_in,
                              void* d_out, int out_size, void* d_ws, size_t ws_size,
                              hipStream_t stream)
{
    (void)in_sizes; (void)n_in; (void)out_size; (void)ws_size;
    const float* emb    = (const float*)d_in[0];
    const int*   labels = (const int*)d_in[1];
    const float* weight = (const float*)d_in[2];
    float* out = (float*)d_out;

    float*  psum    = (float*)d_ws;                    // [NCH][BATCH]  3.2 MB
    float*  zlabel  = psum + (size_t)NCH * BATCH;      // [BATCH]
    float*  rowloss = zlabel + BATCH;                  // [BATCH]
    ushort* eP      = (ushort*)(rowloss + BATCH);      // packed bf16 E frags

    cvt_pack_e<<<(BATCH * EMBED / 8) / 256, 256, 0, stream>>>(emb, eP);
    arc_fused64<<<NCH, 512, 0, stream>>>(eP, labels, weight, psum, zlabel);
    arc_reduce<<<BATCH, 256, 0, stream>>>(psum, zlabel, rowloss);
    arc_mean<<<1, 512, 0, stream>>>(rowloss, out);
}